// Round 2
// baseline (330.871 us; speedup 1.0000x reference)
//
#include <hip/hip_runtime.h>

#define N_NODES 100000
#define N_EDGES 1600000
#define F_IN    128
#define F_OUT   32

__global__ void deg_init_kernel(float* __restrict__ deg) {
    int i = blockIdx.x * blockDim.x + threadIdx.x;
    if (i < N_NODES) deg[i] = 1.0f;  // self loop contributes 1
}

__global__ void deg_accum_kernel(const int* __restrict__ ei, float* __restrict__ deg) {
    int e = blockIdx.x * blockDim.x + threadIdx.x;
    if (e < N_EDGES) {
        int d = ei[N_EDGES + e];  // dst row
        atomicAdd(&deg[d], 1.0f);
    }
}

__global__ void dinv_kernel(const float* __restrict__ deg, float* __restrict__ dinv) {
    int i = blockIdx.x * blockDim.x + threadIdx.x;
    if (i < N_NODES) dinv[i] = rsqrtf(deg[i]);
}

// h = x @ W ; one thread per output element, 32 lanes share a row.
__global__ void matmul_kernel(const float* __restrict__ x, const float* __restrict__ W,
                              float* __restrict__ h) {
    __shared__ float Ws[F_IN * F_OUT];  // 16 KB
    for (int t = threadIdx.x; t < F_IN * F_OUT; t += blockDim.x) Ws[t] = W[t];
    __syncthreads();
    int idx = blockIdx.x * blockDim.x + threadIdx.x;
    int row = idx >> 5;
    int col = idx & 31;
    if (row < N_NODES) {
        const float* xr = x + (size_t)row * F_IN;
        float acc = 0.0f;
#pragma unroll
        for (int k = 0; k < F_IN; ++k) acc += xr[k] * Ws[k * F_OUT + col];
        h[(size_t)row * F_OUT + col] = acc;
    }
}

// out[i][j] = b[j] + h[i][j] * dinv[i]^2   (self-loop term; fully overwrites out)
__global__ void out_init_kernel(const float* __restrict__ h, const float* __restrict__ dinv,
                                const float* __restrict__ b, float* __restrict__ out) {
    int idx = blockIdx.x * blockDim.x + threadIdx.x;
    int row = idx >> 5;
    int col = idx & 31;
    if (row < N_NODES) {
        float dv = dinv[row];
        out[idx] = b[col] + h[idx] * dv * dv;
    }
}

// per edge: out[dst][j] += h[src][j] * dinv[src]*dinv[dst], 32 lanes per edge
__global__ void scatter_kernel(const int* __restrict__ ei, const float* __restrict__ h,
                               const float* __restrict__ dinv, float* __restrict__ out) {
    long long idx = (long long)blockIdx.x * blockDim.x + threadIdx.x;
    int e = (int)(idx >> 5);
    int j = (int)(idx & 31);
    if (e < N_EDGES) {
        int s = ei[e];
        int d = ei[N_EDGES + e];
        float nrm = dinv[s] * dinv[d];
        float val = h[(size_t)s * F_OUT + j] * nrm;
        atomicAdd(&out[(size_t)d * F_OUT + j], val);
    }
}

extern "C" void kernel_launch(void* const* d_in, const int* in_sizes, int n_in,
                              void* d_out, int out_size, void* d_ws, size_t ws_size,
                              hipStream_t stream) {
    const float* x  = (const float*)d_in[0];
    const int*   ei = (const int*)d_in[1];   // int32 on device (harness converts)
    const float* W  = (const float*)d_in[2];
    const float* b  = (const float*)d_in[3];
    float* out = (float*)d_out;

    float* deg  = (float*)d_ws;              // N_NODES floats
    float* dinv = deg + N_NODES;             // N_NODES floats
    float* h    = dinv + N_NODES;            // N_NODES * F_OUT floats

    const int B = 256;

    deg_init_kernel<<<(N_NODES + B - 1) / B, B, 0, stream>>>(deg);
    deg_accum_kernel<<<(N_EDGES + B - 1) / B, B, 0, stream>>>(ei, deg);
    dinv_kernel<<<(N_NODES + B - 1) / B, B, 0, stream>>>(deg, dinv);

    long long hw = (long long)N_NODES * F_OUT;  // 3.2M
    matmul_kernel<<<(int)((hw + B - 1) / B), B, 0, stream>>>(x, W, h);
    out_init_kernel<<<(int)((hw + B - 1) / B), B, 0, stream>>>(h, dinv, b, out);

    long long sw = (long long)N_EDGES * 32;     // 51.2M
    scatter_kernel<<<(int)((sw + B - 1) / B), B, 0, stream>>>(ei, h, dinv, out);
}